// Round 1
// baseline (378.071 us; speedup 1.0000x reference)
//
#include <hip/hip_runtime.h>
#include <math.h>

// Problem constants
#define NPIX   131072      // 32 * 64 * 64 pixels
#define KCODES 512
#define DDIM   64
#define HWSZ   4096        // 64*64
#define NELEM  8388608     // NPIX * DDIM

// d_out layout (fp32): [0]=loss, [1..1+NELEM)=q_nchw, [1+NELEM]=perplexity,
// [2+NELEM .. 2+2*NELEM)=q_nhwc flat
#define OUT_NCHW_OFF 1
#define OUT_PERP_IDX (1 + NELEM)
#define OUT_NHWC_OFF (2 + NELEM)

// ws layout (fp32 words): [0]=loss accum, [16..16+512)=norms, [544..1056)=counts(uint)
#define WS_NORM_OFF 16
#define WS_CNT_OFF  544

__global__ __launch_bounds__(512) void vq_norms(const float* __restrict__ emb,
                                                float* __restrict__ ws) {
    int k = threadIdx.x;  // 512 threads
    const float4* e4 = reinterpret_cast<const float4*>(emb + k * DDIM);
    float s = 0.f;
#pragma unroll
    for (int i = 0; i < 16; ++i) {
        float4 v = e4[i];
        s = fmaf(v.x, v.x, s);
        s = fmaf(v.y, v.y, s);
        s = fmaf(v.z, v.z, s);
        s = fmaf(v.w, v.w, s);
    }
    ws[WS_NORM_OFF + k] = s;
}

__global__ __launch_bounds__(256) void vq_main(const float* __restrict__ in,
                                               const float* __restrict__ emb,
                                               float* __restrict__ out,
                                               float* __restrict__ ws) {
    __shared__ float    q_lds[64 * 65];   // padded tile: 64 pixels x 64 ch
    __shared__ int      idx_lds[256];
    __shared__ unsigned cnt_lds[KCODES];
    __shared__ float    red[4];

    const int t = threadIdx.x;
    cnt_lds[t] = 0u;
    cnt_lds[t + 256] = 0u;
    __syncthreads();

    const int pix0 = blockIdx.x << 8;   // 256 pixels per block, never straddles images
    const int b    = pix0 >> 12;        // image index
    const int hwb  = pix0 & (HWSZ - 1); // hw base within image

    // Load this thread's pixel vector (coalesced across lanes; stride HWSZ per channel)
    const float* inb = in + b * (DDIM * HWSZ) + hwb + t;
    float x[DDIM];
#pragma unroll
    for (int c = 0; c < DDIM; ++c) x[c] = inb[c * HWSZ];
    float x2 = 0.f;
#pragma unroll
    for (int c = 0; c < DDIM; ++c) x2 = fmaf(x[c], x[c], x2);

    // Distance argmin: dist_k = |e_k|^2 - 2 x.e_k  (|x|^2 added only for loss)
    const float* __restrict__ nrm = ws + WS_NORM_OFF;
    float best = 3.4e38f;
    int   bidx = 0;
    for (int k = 0; k < KCODES; k += 8) {
        float acc[8];
#pragma unroll
        for (int j = 0; j < 8; ++j) acc[j] = 0.f;
#pragma unroll
        for (int c = 0; c < DDIM; c += 4) {
#pragma unroll
            for (int j = 0; j < 8; ++j) {
                // wave-uniform address -> scalar-load promotable
                const float4 e = *reinterpret_cast<const float4*>(emb + (k + j) * DDIM + c);
                acc[j] = fmaf(x[c + 0], e.x, acc[j]);
                acc[j] = fmaf(x[c + 1], e.y, acc[j]);
                acc[j] = fmaf(x[c + 2], e.z, acc[j]);
                acc[j] = fmaf(x[c + 3], e.w, acc[j]);
            }
        }
#pragma unroll
        for (int j = 0; j < 8; ++j) {
            float dj = fmaf(-2.f, acc[j], nrm[k + j]);
            if (dj < best) { best = dj; bidx = k + j; }  // strict < => first min (ref argmin)
        }
    }

    // loss contribution: |x - e_best|^2 = x2 + best
    float lp = x2 + best;
#pragma unroll
    for (int o = 32; o > 0; o >>= 1) lp += __shfl_xor(lp, o, 64);
    if ((t & 63) == 0) red[t >> 6] = lp;

    idx_lds[t] = bidx;
    atomicAdd(&cnt_lds[bidx], 1u);
    __syncthreads();

    if (t == 0) atomicAdd(ws, red[0] + red[1] + red[2] + red[3]);
    unsigned* gcnt = reinterpret_cast<unsigned*>(ws) + WS_CNT_OFF;
    atomicAdd(gcnt + t, cnt_lds[t]);
    atomicAdd(gcnt + t + 256, cnt_lds[t + 256]);

    // Epilogue: 4 subtiles of 64 pixels; stage gathered rows in padded LDS so both
    // NHWC and NCHW writes are fully coalesced and LDS reads conflict-free.
    float* out2 = out + OUT_NCHW_OFF;   // NCHW
    float* out3 = out + OUT_NHWC_OFF;   // NHWC flat (float2-aligned, NOT float4-aligned)
    const float2* emb2 = reinterpret_cast<const float2*>(emb);
    float2* out3_2 = reinterpret_cast<float2*>(out3);

    for (int s = 0; s < 4; ++s) {
        // fill: 64 pixels x 32 float2 = 2048 float2, 256 threads -> 8 iters
#pragma unroll
        for (int it = 0; it < 8; ++it) {
            int fid = it * 256 + t;
            int pp  = fid >> 5;        // 0..63 local pixel
            int c2  = fid & 31;        // float2 column
            int row = idx_lds[s * 64 + pp];
            float2 v = emb2[row * 32 + c2];
            out3_2[(size_t)(pix0 + s * 64 + pp) * 32 + c2] = v;  // coalesced NHWC
            q_lds[pp * 65 + c2 * 2 + 0] = v.x;
            q_lds[pp * 65 + c2 * 2 + 1] = v.y;
        }
        __syncthreads();
        // drain NCHW: 64 ch x 64 hw, lanes sweep hw -> coalesced; (hwl+c)%32 -> no conflicts
#pragma unroll
        for (int it = 0; it < 16; ++it) {
            int did = it * 256 + t;
            int c   = did >> 6;
            int hwl = did & 63;
            out2[(size_t)(b * DDIM + c) * HWSZ + hwb + s * 64 + hwl] = q_lds[hwl * 65 + c];
        }
        __syncthreads();
    }
}

__global__ __launch_bounds__(256) void vq_fin(float* __restrict__ out,
                                              const float* __restrict__ ws) {
    const unsigned* cnt = reinterpret_cast<const unsigned*>(ws) + WS_CNT_OFF;
    int t = threadIdx.x;  // 256
    double s = 0.0;
#pragma unroll
    for (int k = t; k < KCODES; k += 256) {
        double p = (double)cnt[k] / (double)NPIX;
        s += p * log(p + 1e-10);
    }
#pragma unroll
    for (int o = 32; o > 0; o >>= 1) s += __shfl_xor(s, o, 64);
    __shared__ double rd[4];
    if ((t & 63) == 0) rd[t >> 6] = s;
    __syncthreads();
    if (t == 0) {
        double tot = rd[0] + rd[1] + rd[2] + rd[3];
        out[OUT_PERP_IDX] = (float)exp(-tot);
        out[0] = 0.25f * ws[0] / (float)NELEM;
    }
}

extern "C" void kernel_launch(void* const* d_in, const int* in_sizes, int n_in,
                              void* d_out, int out_size, void* d_ws, size_t ws_size,
                              hipStream_t stream) {
    const float* in  = (const float*)d_in[0];
    const float* emb = (const float*)d_in[1];
    float* out = (float*)d_out;
    float* ws  = (float*)d_ws;

    // zero loss accumulator + norms + counts (ws is re-poisoned before every launch)
    hipMemsetAsync(d_ws, 0, (WS_CNT_OFF + KCODES) * sizeof(float), stream);
    vq_norms<<<1, 512, 0, stream>>>(emb, ws);
    vq_main<<<NPIX / 256, 256, 0, stream>>>(in, emb, out, ws);
    vq_fin<<<1, 256, 0, stream>>>(out, ws);
}